// Round 1
// baseline (247.672 us; speedup 1.0000x reference)
//
#include <hip/hip_runtime.h>

// LIF recurrence: mem = tau*mem + x[t]; spike = (mem > v_th); mem *= (1-spike)
// Shapes: x [T,B,C,H,W] fp32, mem0 [1,C,H,W] fp32, out spikes [T,B,C,H,W] fp32.
// T=4, B=64, C=128, H=W=32. Memory-bound elementwise scan, ~268 MB ideal traffic.
//
// This version attacks the latency-bound profile of the previous kernel
// (VGPR=16 -> only 1 outstanding load/wave, 2.4 TB/s eff BW):
//  - IPT=2 elements/thread, ALL IPT*T=8 float4 loads issued before any use
//    (8 outstanding vmem ops per wave instead of 1).
//  - Non-temporal stores: output is write-once/never-read; keep it from
//    evicting x out of the 256 MiB Infinity Cache across iterations.

#ifndef LIF_T
#define LIF_T 4
#endif

#ifndef IPT
#define IPT 2
#endif

typedef float vfloat4 __attribute__((ext_vector_type(4)));

__device__ __forceinline__ void lif_step(float4& mem, const float4 xt, float4& s) {
    const float TAU = 0.25f;
    const float V_TH = 1.0f;
    mem.x = TAU * mem.x + xt.x;
    mem.y = TAU * mem.y + xt.y;
    mem.z = TAU * mem.z + xt.z;
    mem.w = TAU * mem.w + xt.w;
    s.x = (mem.x > V_TH) ? 1.0f : 0.0f;
    s.y = (mem.y > V_TH) ? 1.0f : 0.0f;
    s.z = (mem.z > V_TH) ? 1.0f : 0.0f;
    s.w = (mem.w > V_TH) ? 1.0f : 0.0f;
    mem.x = (mem.x > V_TH) ? 0.0f : mem.x;
    mem.y = (mem.y > V_TH) ? 0.0f : mem.y;
    mem.z = (mem.z > V_TH) ? 0.0f : mem.z;
    mem.w = (mem.w > V_TH) ? 0.0f : mem.w;
}

__global__ __launch_bounds__(256) void
lif_kernel(const float4* __restrict__ x,     // [T, N4] float4 view
           const float4* __restrict__ mem0,  // [CHW4] float4 view (broadcast over B)
           float4* __restrict__ out,         // [T, N4]
           int n4, int chw4_mask) {
    const int stride = gridDim.x * blockDim.x;
    const int base   = blockIdx.x * blockDim.x + threadIdx.x;

    if (base + (IPT - 1) * stride < n4) {
        // Fast path (always taken for the fixed problem shape: n4 = 2^21,
        // divisible by block*IPT): issue every load before any compute.
        float4 xv[IPT][LIF_T];
#pragma unroll
        for (int j = 0; j < IPT; ++j) {
            const size_t ij = (size_t)base + (size_t)j * (size_t)stride;
#pragma unroll
            for (int t = 0; t < LIF_T; ++t)
                xv[j][t] = x[(size_t)t * n4 + ij];
        }

#pragma unroll
        for (int j = 0; j < IPT; ++j) {
            const size_t ij = (size_t)base + (size_t)j * (size_t)stride;
            float4 mem = mem0[(int)ij & chw4_mask];
#pragma unroll
            for (int t = 0; t < LIF_T; ++t) {
                float4 s;
                lif_step(mem, xv[j][t], s);
                // Non-temporal 16B store: don't allocate the (never re-read)
                // output in L2/L3, preserving x's Infinity-Cache residency.
                __builtin_nontemporal_store(
                    (vfloat4){s.x, s.y, s.z, s.w},
                    (vfloat4*)&out[(size_t)t * n4 + ij]);
            }
        }
    } else {
        // Tail path (never taken at the bench shape, kept for generality).
        for (int j = 0; j < IPT; ++j) {
            const int ij = base + j * stride;
            if (ij >= n4) continue;
            float4 mem = mem0[ij & chw4_mask];
            for (int t = 0; t < LIF_T; ++t) {
                float4 s;
                lif_step(mem, x[(size_t)t * n4 + ij], s);
                out[(size_t)t * n4 + ij] = s;
            }
        }
    }
}

extern "C" void kernel_launch(void* const* d_in, const int* in_sizes, int n_in,
                              void* d_out, int out_size, void* d_ws, size_t ws_size,
                              hipStream_t stream) {
    const float* x    = (const float*)d_in[0];   // [T,B,C,H,W]
    const float* mem0 = (const float*)d_in[1];   // [1,C,H,W]
    float* out        = (float*)d_out;           // [T,B,C,H,W]

    const int T = LIF_T;
    const int total = in_sizes[0];        // T*B*C*H*W
    const int bchw  = total / T;          // per-timestep elements
    const int n4    = bchw / 4;           // float4 count per timestep
    const int chw4  = in_sizes[1] / 4;    // mem0 float4 count (power of 2)

    const int block = 256;
    const int grid  = (n4 + block * IPT - 1) / (block * IPT);

    lif_kernel<<<grid, block, 0, stream>>>(
        (const float4*)x, (const float4*)mem0, (float4*)out,
        n4, chw4 - 1);
}

// Round 2
// 230.339 us; speedup vs baseline: 1.0753x; 1.0753x over previous
//
#include <hip/hip_runtime.h>

// LIF recurrence: mem = tau*mem + x[t]; spike = (mem > v_th); mem *= (1-spike)
// x [T,B,C,H,W] fp32, mem0 [1,C,H,W] fp32, out [T,B,C,H,W] fp32.
// T=4, B=64, C=128, H=W=32. n4 = 2^21 float4 per timestep.
//
// Latency-bound history:
//   R0: VGPR=16, 1 outstanding load/wave -> 84us, 2.4 TB/s
//   R1: array-hoist was sunk by the scheduler (VGPR=28), grid halved -> 104us
// This version FORCES MLP: named float4 registers + sched_barrier(0) fence
// between the load block and compute, so all 10 loads/thread are in flight.
// mem0 loads issue first so the first compute waits with 8 loads still
// outstanding instead of draining vmcnt to 0.

#ifndef LIF_T
#define LIF_T 4
#endif

#define BLOCK 256

__device__ __forceinline__ float4 lif_step(float4& mem, const float4 xt) {
    const float TAU = 0.25f;
    const float V_TH = 1.0f;
    float4 s;
    mem.x = TAU * mem.x + xt.x;
    mem.y = TAU * mem.y + xt.y;
    mem.z = TAU * mem.z + xt.z;
    mem.w = TAU * mem.w + xt.w;
    s.x = (mem.x > V_TH) ? 1.0f : 0.0f;
    s.y = (mem.y > V_TH) ? 1.0f : 0.0f;
    s.z = (mem.z > V_TH) ? 1.0f : 0.0f;
    s.w = (mem.w > V_TH) ? 1.0f : 0.0f;
    mem.x = (mem.x > V_TH) ? 0.0f : mem.x;
    mem.y = (mem.y > V_TH) ? 0.0f : mem.y;
    mem.z = (mem.z > V_TH) ? 0.0f : mem.z;
    mem.w = (mem.w > V_TH) ? 0.0f : mem.w;
    return s;
}

__global__ __launch_bounds__(BLOCK, 8) void
lif_kernel(const float4* __restrict__ x,     // [T, N4] float4 view
           const float4* __restrict__ mem0,  // [CHW4] float4 view (broadcast over B)
           float4* __restrict__ out,         // [T, N4]
           int n4, int chw4_mask) {
    // Two block-contiguous float4 elements per thread: i0 and i0+BLOCK.
    // Both perfectly coalesced; grid = n4 / (2*BLOCK) = 4096 blocks.
    const int i0 = blockIdx.x * (2 * BLOCK) + threadIdx.x;
    const int i1 = i0 + BLOCK;

    if (i1 < n4) {
        // ---- load block: 10 independent loads, issued before ANY use ----
        float4 ma  = mem0[i0 & chw4_mask];
        float4 mb  = mem0[i1 & chw4_mask];
        float4 xa0 = x[i0];
        float4 xb0 = x[i1];
        float4 xa1 = x[n4 + i0];
        float4 xb1 = x[n4 + i1];
        float4 xa2 = x[2 * n4 + i0];
        float4 xb2 = x[2 * n4 + i1];
        float4 xa3 = x[3 * n4 + i0];
        float4 xb3 = x[3 * n4 + i1];
        // Scheduler fence: nothing (in particular no load) may cross this.
        __builtin_amdgcn_sched_barrier(0);

        // ---- compute + store, a/b interleaved for ILP ----
        float4 s;
        s = lif_step(ma, xa0); out[i0] = s;
        s = lif_step(mb, xb0); out[i1] = s;
        s = lif_step(ma, xa1); out[n4 + i0] = s;
        s = lif_step(mb, xb1); out[n4 + i1] = s;
        s = lif_step(ma, xa2); out[2 * n4 + i0] = s;
        s = lif_step(mb, xb2); out[2 * n4 + i1] = s;
        s = lif_step(ma, xa3); out[3 * n4 + i0] = s;
        s = lif_step(mb, xb3); out[3 * n4 + i1] = s;
    } else {
        // Tail (never taken at the bench shape: n4 divisible by 2*BLOCK).
        for (int k = 0; k < 2; ++k) {
            const int i = i0 + k * BLOCK;
            if (i >= n4) continue;
            float4 mem = mem0[i & chw4_mask];
            for (int t = 0; t < LIF_T; ++t) {
                float4 s = lif_step(mem, x[(size_t)t * n4 + i]);
                out[(size_t)t * n4 + i] = s;
            }
        }
    }
}

extern "C" void kernel_launch(void* const* d_in, const int* in_sizes, int n_in,
                              void* d_out, int out_size, void* d_ws, size_t ws_size,
                              hipStream_t stream) {
    const float* x    = (const float*)d_in[0];   // [T,B,C,H,W]
    const float* mem0 = (const float*)d_in[1];   // [1,C,H,W]
    float* out        = (float*)d_out;           // [T,B,C,H,W]

    const int T = LIF_T;
    const int total = in_sizes[0];        // T*B*C*H*W
    const int bchw  = total / T;          // per-timestep elements
    const int n4    = bchw / 4;           // float4 count per timestep
    const int chw4  = in_sizes[1] / 4;    // mem0 float4 count (power of 2)

    const int block = BLOCK;
    const int grid  = (n4 + block * 2 - 1) / (block * 2);

    lif_kernel<<<grid, block, 0, stream>>>(
        (const float4*)x, (const float4*)mem0, (float4*)out,
        n4, chw4 - 1);
}

// Round 3
// 229.928 us; speedup vs baseline: 1.0772x; 1.0018x over previous
//
#include <hip/hip_runtime.h>

// LIF recurrence: mem = tau*mem + x[t]; spike = (mem > v_th); mem *= (1-spike)
// x [T,B,C,H,W] fp32, mem0 [1,C,H,W] fp32, out [T,B,C,H,W] fp32.
// T=4, B=64, C=128, H=W=32. n4 = 2^21 float4 per timestep.
//
// History (per-dispatch):
//   R0: 1-elem/thread, loads serialized          -> 84us, 2.45 TB/s
//   R1: array hoist (sunk by scheduler) + nt st  -> 104us (grid halved)
//   R2: named-reg hoist + sched_barrier, 10 deep -> ~81us. MLP theory dead:
//       in-flight bytes were never the limiter (8.4 MB device-wide at R0).
// Remaining theory: STREAM COUNT. copy(1R+1W)=6.3 TB/s, fill(1W)=6.6 TB/s,
// ours (4R+4W planes at power-of-2 offsets, all concurrent) = 2.5 TB/s.
// This version sweeps ONE t-plane at a time: t-loop outermost, a/b register
// ping-pong, loads(t+1) issued BEFORE stores(t) so no store-drain stall.
// Grid = 2048 blocks = exactly one full-residency round (32 waves/CU).

#ifndef LIF_T
#define LIF_T 4
#endif

#define BLOCK 256
#define IPT 4   // block-contiguous float4 per thread -> 16KB/block per plane

__device__ __forceinline__ float4 lif_step(float4& mem, const float4 xt) {
    const float TAU = 0.25f;
    const float V_TH = 1.0f;
    float4 s;
    mem.x = TAU * mem.x + xt.x;
    mem.y = TAU * mem.y + xt.y;
    mem.z = TAU * mem.z + xt.z;
    mem.w = TAU * mem.w + xt.w;
    s.x = (mem.x > V_TH) ? 1.0f : 0.0f;
    s.y = (mem.y > V_TH) ? 1.0f : 0.0f;
    s.z = (mem.z > V_TH) ? 1.0f : 0.0f;
    s.w = (mem.w > V_TH) ? 1.0f : 0.0f;
    mem.x = (mem.x > V_TH) ? 0.0f : mem.x;
    mem.y = (mem.y > V_TH) ? 0.0f : mem.y;
    mem.z = (mem.z > V_TH) ? 0.0f : mem.z;
    mem.w = (mem.w > V_TH) ? 0.0f : mem.w;
    return s;
}

__global__ __launch_bounds__(BLOCK) void
lif_kernel(const float4* __restrict__ x,     // [T, N4] float4 view
           const float4* __restrict__ mem0,  // [CHW4] float4 view (broadcast over B)
           float4* __restrict__ out,         // [T, N4]
           int n4, int chw4_mask) {
    const int base = blockIdx.x * (BLOCK * IPT) + threadIdx.x;
    const int i0 = base;
    const int i1 = base + BLOCK;
    const int i2 = base + 2 * BLOCK;
    const int i3 = base + 3 * BLOCK;

    if (i3 < n4) {
        // Membrane state (broadcast init).
        float4 m0 = mem0[i0 & chw4_mask];
        float4 m1 = mem0[i1 & chw4_mask];
        float4 m2 = mem0[i2 & chw4_mask];
        float4 m3 = mem0[i3 & chw4_mask];

        // t=0 plane loads (a-set).
        float4 a0 = x[i0], a1 = x[i1], a2 = x[i2], a3 = x[i3];
        float4 b0, b1, b2, b3;

        // ---- t=0: compute on a, prefetch t=1 into b, then store ----
        a0 = lif_step(m0, a0); a1 = lif_step(m1, a1);
        a2 = lif_step(m2, a2); a3 = lif_step(m3, a3);
        b0 = x[n4 + i0]; b1 = x[n4 + i1]; b2 = x[n4 + i2]; b3 = x[n4 + i3];
        __builtin_amdgcn_sched_barrier(0);   // keep prefetch above the stores
        out[i0] = a0; out[i1] = a1; out[i2] = a2; out[i3] = a3;

        // ---- t=1: compute on b, prefetch t=2 into a, store ----
        b0 = lif_step(m0, b0); b1 = lif_step(m1, b1);
        b2 = lif_step(m2, b2); b3 = lif_step(m3, b3);
        a0 = x[2 * n4 + i0]; a1 = x[2 * n4 + i1];
        a2 = x[2 * n4 + i2]; a3 = x[2 * n4 + i3];
        __builtin_amdgcn_sched_barrier(0);
        out[n4 + i0] = b0; out[n4 + i1] = b1;
        out[n4 + i2] = b2; out[n4 + i3] = b3;

        // ---- t=2: compute on a, prefetch t=3 into b, store ----
        a0 = lif_step(m0, a0); a1 = lif_step(m1, a1);
        a2 = lif_step(m2, a2); a3 = lif_step(m3, a3);
        b0 = x[3 * n4 + i0]; b1 = x[3 * n4 + i1];
        b2 = x[3 * n4 + i2]; b3 = x[3 * n4 + i3];
        __builtin_amdgcn_sched_barrier(0);
        out[2 * n4 + i0] = a0; out[2 * n4 + i1] = a1;
        out[2 * n4 + i2] = a2; out[2 * n4 + i3] = a3;

        // ---- t=3: compute on b, store ----
        b0 = lif_step(m0, b0); b1 = lif_step(m1, b1);
        b2 = lif_step(m2, b2); b3 = lif_step(m3, b3);
        out[3 * n4 + i0] = b0; out[3 * n4 + i1] = b1;
        out[3 * n4 + i2] = b2; out[3 * n4 + i3] = b3;
    } else {
        // Tail (never taken at the bench shape: n4 divisible by BLOCK*IPT).
        for (int k = 0; k < IPT; ++k) {
            const int i = base + k * BLOCK;
            if (i >= n4) continue;
            float4 mem = mem0[i & chw4_mask];
            for (int t = 0; t < LIF_T; ++t) {
                float4 s = lif_step(mem, x[(size_t)t * n4 + i]);
                out[(size_t)t * n4 + i] = s;
            }
        }
    }
}

extern "C" void kernel_launch(void* const* d_in, const int* in_sizes, int n_in,
                              void* d_out, int out_size, void* d_ws, size_t ws_size,
                              hipStream_t stream) {
    const float* x    = (const float*)d_in[0];   // [T,B,C,H,W]
    const float* mem0 = (const float*)d_in[1];   // [1,C,H,W]
    float* out        = (float*)d_out;           // [T,B,C,H,W]

    const int T = LIF_T;
    const int total = in_sizes[0];        // T*B*C*H*W
    const int bchw  = total / T;          // per-timestep elements
    const int n4    = bchw / 4;           // float4 count per timestep
    const int chw4  = in_sizes[1] / 4;    // mem0 float4 count (power of 2)

    const int block = BLOCK;
    const int grid  = (n4 + block * IPT - 1) / (block * IPT);

    lif_kernel<<<grid, block, 0, stream>>>(
        (const float4*)x, (const float4*)mem0, (float4*)out,
        n4, chw4 - 1);
}

// Round 5
// 221.834 us; speedup vs baseline: 1.1165x; 1.0365x over previous
//
#include <hip/hip_runtime.h>
#include <stdint.h>

// LIF recurrence: mem = tau*mem + x[t]; spike = (mem > v_th); mem *= (1-spike)
// x [T,B,C,H,W] fp32, mem0 [1,C,H,W] fp32, out [T,B,C,H,W] fp32.
// T=4, B=64, C=128, H=W=32. n4 = 2^21 float4 per timestep.
//
// Falsification ledger (per-dispatch kernel time; harness dur = kernel+~147us):
//   R0: 1-elem/thread, serialized loads            84us
//   R1: array hoist (sunk) + builtin nt-store     104us; FETCH unchanged
//   R2: named-reg hoist + sched_barrier, 10-deep  ~81us -> per-wave MLP null
//   R3: t-plane sweep, a/b ping-pong prefetch     ~81us -> stream-count null
//   R4: asm `sc1 nt` stores -> CORRECTNESS FAIL (bypasses the cache level the
//       harness readback uses; scope-bypass stores are banned here)
// All structures pin at ~81-84us = ~3.3 TB/s demand (268MB), 52% of the
// 6.3 TB/s copy ceiling; VALU 4%, no pipe saturated. FETCH=66MB invariant
// (likely gfx94x-formula undercount of 128B read requests: real ~134MB).
//
// R5 (last safe lever): NON-TEMPORAL LOADS on x via __builtin_nontemporal_load
// (compiler encoding, coherence-safe). x is dead-on-read each iteration (the
// harness's 537MB inter-iteration fill cycles IF$ anyway); evict-first x lines
// stop churning out's dirty lines mid-kernel. Stores are plain (proven safe).
// If null -> structural mixed-stream ceiling; declare with arithmetic.

#ifndef LIF_T
#define LIF_T 4
#endif

#define BLOCK 256
#define IPT 4   // block-contiguous float4 per thread: each block owns a
                // contiguous 16KB window per t-plane

typedef float vfloat4 __attribute__((ext_vector_type(4)));

__device__ __forceinline__ float4 load_nt(const float4* p) {
    vfloat4 v = __builtin_nontemporal_load((const vfloat4*)p);
    return make_float4(v.x, v.y, v.z, v.w);
}

__device__ __forceinline__ float4 lif_step(float4& mem, const float4 xt) {
    const float TAU = 0.25f;
    const float V_TH = 1.0f;
    float4 s;
    mem.x = TAU * mem.x + xt.x;
    mem.y = TAU * mem.y + xt.y;
    mem.z = TAU * mem.z + xt.z;
    mem.w = TAU * mem.w + xt.w;
    s.x = (mem.x > V_TH) ? 1.0f : 0.0f;
    s.y = (mem.y > V_TH) ? 1.0f : 0.0f;
    s.z = (mem.z > V_TH) ? 1.0f : 0.0f;
    s.w = (mem.w > V_TH) ? 1.0f : 0.0f;
    mem.x = (mem.x > V_TH) ? 0.0f : mem.x;
    mem.y = (mem.y > V_TH) ? 0.0f : mem.y;
    mem.z = (mem.z > V_TH) ? 0.0f : mem.z;
    mem.w = (mem.w > V_TH) ? 0.0f : mem.w;
    return s;
}

__global__ __launch_bounds__(BLOCK) void
lif_kernel(const float4* __restrict__ x,     // [T, N4] float4 view
           const float4* __restrict__ mem0,  // [CHW4] float4 view (broadcast over B)
           float4* __restrict__ out,         // [T, N4]
           int n4, int chw4_mask) {
    const int base = blockIdx.x * (BLOCK * IPT) + threadIdx.x;
    const int i0 = base;
    const int i1 = base + BLOCK;
    const int i2 = base + 2 * BLOCK;
    const int i3 = base + 3 * BLOCK;

    if (i3 < n4) {
        float4 m0 = mem0[i0 & chw4_mask];
        float4 m1 = mem0[i1 & chw4_mask];
        float4 m2 = mem0[i2 & chw4_mask];
        float4 m3 = mem0[i3 & chw4_mask];

        // t=0 plane loads (a-set), non-temporal (x is dead-on-read).
        float4 a0 = load_nt(&x[i0]), a1 = load_nt(&x[i1]);
        float4 a2 = load_nt(&x[i2]), a3 = load_nt(&x[i3]);
        float4 b0, b1, b2, b3;

        // ---- t=0: compute on a, prefetch t=1 into b, store ----
        a0 = lif_step(m0, a0); a1 = lif_step(m1, a1);
        a2 = lif_step(m2, a2); a3 = lif_step(m3, a3);
        b0 = load_nt(&x[n4 + i0]); b1 = load_nt(&x[n4 + i1]);
        b2 = load_nt(&x[n4 + i2]); b3 = load_nt(&x[n4 + i3]);
        __builtin_amdgcn_sched_barrier(0);   // keep prefetch above the stores
        out[i0] = a0; out[i1] = a1; out[i2] = a2; out[i3] = a3;

        // ---- t=1 ----
        b0 = lif_step(m0, b0); b1 = lif_step(m1, b1);
        b2 = lif_step(m2, b2); b3 = lif_step(m3, b3);
        a0 = load_nt(&x[2 * n4 + i0]); a1 = load_nt(&x[2 * n4 + i1]);
        a2 = load_nt(&x[2 * n4 + i2]); a3 = load_nt(&x[2 * n4 + i3]);
        __builtin_amdgcn_sched_barrier(0);
        out[n4 + i0] = b0; out[n4 + i1] = b1;
        out[n4 + i2] = b2; out[n4 + i3] = b3;

        // ---- t=2 ----
        a0 = lif_step(m0, a0); a1 = lif_step(m1, a1);
        a2 = lif_step(m2, a2); a3 = lif_step(m3, a3);
        b0 = load_nt(&x[3 * n4 + i0]); b1 = load_nt(&x[3 * n4 + i1]);
        b2 = load_nt(&x[3 * n4 + i2]); b3 = load_nt(&x[3 * n4 + i3]);
        __builtin_amdgcn_sched_barrier(0);
        out[2 * n4 + i0] = a0; out[2 * n4 + i1] = a1;
        out[2 * n4 + i2] = a2; out[2 * n4 + i3] = a3;

        // ---- t=3 ----
        b0 = lif_step(m0, b0); b1 = lif_step(m1, b1);
        b2 = lif_step(m2, b2); b3 = lif_step(m3, b3);
        out[3 * n4 + i0] = b0; out[3 * n4 + i1] = b1;
        out[3 * n4 + i2] = b2; out[3 * n4 + i3] = b3;
    } else {
        // Tail (never taken at the bench shape: n4 divisible by BLOCK*IPT).
        for (int k = 0; k < IPT; ++k) {
            const int i = base + k * BLOCK;
            if (i >= n4) continue;
            float4 mem = mem0[i & chw4_mask];
            for (int t = 0; t < LIF_T; ++t) {
                float4 s = lif_step(mem, x[(size_t)t * n4 + i]);
                out[(size_t)t * n4 + i] = s;
            }
        }
    }
}

extern "C" void kernel_launch(void* const* d_in, const int* in_sizes, int n_in,
                              void* d_out, int out_size, void* d_ws, size_t ws_size,
                              hipStream_t stream) {
    const float* x    = (const float*)d_in[0];   // [T,B,C,H,W]
    const float* mem0 = (const float*)d_in[1];   // [1,C,H,W]
    float* out        = (float*)d_out;           // [T,B,C,H,W]

    const int T = LIF_T;
    const int total = in_sizes[0];        // T*B*C*H*W
    const int bchw  = total / T;          // per-timestep elements
    const int n4    = bchw / 4;           // float4 count per timestep
    const int chw4  = in_sizes[1] / 4;    // mem0 float4 count (power of 2)

    const int block = BLOCK;
    const int grid  = (n4 + block * IPT - 1) / (block * IPT);

    lif_kernel<<<grid, block, 0, stream>>>(
        (const float4*)x, (const float4*)mem0, (float4*)out,
        n4, chw4 - 1);
}

// Round 6
// 219.567 us; speedup vs baseline: 1.1280x; 1.0103x over previous
//
#include <hip/hip_runtime.h>
#include <stdint.h>

// LIF recurrence: mem = tau*mem + x[t]; spike = (mem > v_th); mem *= (1-spike)
// x [T,B,C,H,W] fp32, mem0 [1,C,H,W] fp32, out [T,B,C,H,W] fp32.
// T=4, B=64, C=128, H=W=32. n4 = 2^21 float4 per timestep.
//
// Falsification ledger (kernel time = harness dur - ~147us fixed overhead):
//   R0: serialized loads                           84us
//   R1: sunk array hoist + builtin nt-store       104us (confounded: grid/2)
//   R2: forced 10-deep MLP (sched_barrier)        ~81us -> MLP null
//   R3: t-plane sweep, a/b ping-pong prefetch     ~81us -> stream-count null
//   R4: asm `sc1 nt` stores                        FAIL -> scope-bypass banned
//   R5: + builtin NT LOADS on x                   ~75us -> WIN (+8%): evict-
//       first x lines stop churning out's dirty L3 lines
// Accounting: WRITE=128MiB (exactly out), FETCH=64MiB (exactly half of x ->
// half of x is IF$-resident each iter). HBM 2.6 TB/s during kernel vs 6.6
// the fills prove. VALU 5%, MLP forced-deep twice = null. Latency-class and
// concurrency-class theories all falsified.
//
// R6: add builtin NT STORES (correctness-proven in R1) to the R5 skeleton —
// symmetric twin of the R5 win: out's lines marked evict-first so they don't
// displace the L3-resident half of x mid-kernel. If null -> ledger complete,
// structural ceiling (~3.6 TB/s for this 4R+4W mixed stream) -> ROOFLINE.

#ifndef LIF_T
#define LIF_T 4
#endif

#define BLOCK 256
#define IPT 4   // block-contiguous float4 per thread: 16KB/block per t-plane

typedef float vfloat4 __attribute__((ext_vector_type(4)));

__device__ __forceinline__ float4 load_nt(const float4* p) {
    vfloat4 v = __builtin_nontemporal_load((const vfloat4*)p);
    return make_float4(v.x, v.y, v.z, v.w);
}

__device__ __forceinline__ void store_nt(float4* p, float4 v) {
    vfloat4 d = {v.x, v.y, v.z, v.w};
    __builtin_nontemporal_store(d, (vfloat4*)p);
}

__device__ __forceinline__ float4 lif_step(float4& mem, const float4 xt) {
    const float TAU = 0.25f;
    const float V_TH = 1.0f;
    float4 s;
    mem.x = TAU * mem.x + xt.x;
    mem.y = TAU * mem.y + xt.y;
    mem.z = TAU * mem.z + xt.z;
    mem.w = TAU * mem.w + xt.w;
    s.x = (mem.x > V_TH) ? 1.0f : 0.0f;
    s.y = (mem.y > V_TH) ? 1.0f : 0.0f;
    s.z = (mem.z > V_TH) ? 1.0f : 0.0f;
    s.w = (mem.w > V_TH) ? 1.0f : 0.0f;
    mem.x = (mem.x > V_TH) ? 0.0f : mem.x;
    mem.y = (mem.y > V_TH) ? 0.0f : mem.y;
    mem.z = (mem.z > V_TH) ? 0.0f : mem.z;
    mem.w = (mem.w > V_TH) ? 0.0f : mem.w;
    return s;
}

__global__ __launch_bounds__(BLOCK) void
lif_kernel(const float4* __restrict__ x,     // [T, N4] float4 view
           const float4* __restrict__ mem0,  // [CHW4] float4 view (broadcast over B)
           float4* __restrict__ out,         // [T, N4]
           int n4, int chw4_mask) {
    const int base = blockIdx.x * (BLOCK * IPT) + threadIdx.x;
    const int i0 = base;
    const int i1 = base + BLOCK;
    const int i2 = base + 2 * BLOCK;
    const int i3 = base + 3 * BLOCK;

    if (i3 < n4) {
        float4 m0 = mem0[i0 & chw4_mask];
        float4 m1 = mem0[i1 & chw4_mask];
        float4 m2 = mem0[i2 & chw4_mask];
        float4 m3 = mem0[i3 & chw4_mask];

        // t=0 plane loads (a-set), non-temporal (x is dead-on-read).
        float4 a0 = load_nt(&x[i0]), a1 = load_nt(&x[i1]);
        float4 a2 = load_nt(&x[i2]), a3 = load_nt(&x[i3]);
        float4 b0, b1, b2, b3;

        // ---- t=0: compute on a, prefetch t=1 into b, store ----
        a0 = lif_step(m0, a0); a1 = lif_step(m1, a1);
        a2 = lif_step(m2, a2); a3 = lif_step(m3, a3);
        b0 = load_nt(&x[n4 + i0]); b1 = load_nt(&x[n4 + i1]);
        b2 = load_nt(&x[n4 + i2]); b3 = load_nt(&x[n4 + i3]);
        __builtin_amdgcn_sched_barrier(0);   // keep prefetch above the stores
        store_nt(&out[i0], a0); store_nt(&out[i1], a1);
        store_nt(&out[i2], a2); store_nt(&out[i3], a3);

        // ---- t=1 ----
        b0 = lif_step(m0, b0); b1 = lif_step(m1, b1);
        b2 = lif_step(m2, b2); b3 = lif_step(m3, b3);
        a0 = load_nt(&x[2 * n4 + i0]); a1 = load_nt(&x[2 * n4 + i1]);
        a2 = load_nt(&x[2 * n4 + i2]); a3 = load_nt(&x[2 * n4 + i3]);
        __builtin_amdgcn_sched_barrier(0);
        store_nt(&out[n4 + i0], b0); store_nt(&out[n4 + i1], b1);
        store_nt(&out[n4 + i2], b2); store_nt(&out[n4 + i3], b3);

        // ---- t=2 ----
        a0 = lif_step(m0, a0); a1 = lif_step(m1, a1);
        a2 = lif_step(m2, a2); a3 = lif_step(m3, a3);
        b0 = load_nt(&x[3 * n4 + i0]); b1 = load_nt(&x[3 * n4 + i1]);
        b2 = load_nt(&x[3 * n4 + i2]); b3 = load_nt(&x[3 * n4 + i3]);
        __builtin_amdgcn_sched_barrier(0);
        store_nt(&out[2 * n4 + i0], a0); store_nt(&out[2 * n4 + i1], a1);
        store_nt(&out[2 * n4 + i2], a2); store_nt(&out[2 * n4 + i3], a3);

        // ---- t=3 ----
        b0 = lif_step(m0, b0); b1 = lif_step(m1, b1);
        b2 = lif_step(m2, b2); b3 = lif_step(m3, b3);
        store_nt(&out[3 * n4 + i0], b0); store_nt(&out[3 * n4 + i1], b1);
        store_nt(&out[3 * n4 + i2], b2); store_nt(&out[3 * n4 + i3], b3);
    } else {
        // Tail (never taken at the bench shape: n4 divisible by BLOCK*IPT).
        for (int k = 0; k < IPT; ++k) {
            const int i = base + k * BLOCK;
            if (i >= n4) continue;
            float4 mem = mem0[i & chw4_mask];
            for (int t = 0; t < LIF_T; ++t) {
                float4 s = lif_step(mem, x[(size_t)t * n4 + i]);
                out[(size_t)t * n4 + i] = s;
            }
        }
    }
}

extern "C" void kernel_launch(void* const* d_in, const int* in_sizes, int n_in,
                              void* d_out, int out_size, void* d_ws, size_t ws_size,
                              hipStream_t stream) {
    const float* x    = (const float*)d_in[0];   // [T,B,C,H,W]
    const float* mem0 = (const float*)d_in[1];   // [1,C,H,W]
    float* out        = (float*)d_out;           // [T,B,C,H,W]

    const int T = LIF_T;
    const int total = in_sizes[0];        // T*B*C*H*W
    const int bchw  = total / T;          // per-timestep elements
    const int n4    = bchw / 4;           // float4 count per timestep
    const int chw4  = in_sizes[1] / 4;    // mem0 float4 count (power of 2)

    const int block = BLOCK;
    const int grid  = (n4 + block * IPT - 1) / (block * IPT);

    lif_kernel<<<grid, block, 0, stream>>>(
        (const float4*)x, (const float4*)mem0, (float4*)out,
        n4, chw4 - 1);
}